// Round 5
// baseline (998.516 us; speedup 1.0000x reference)
//
#include <hip/hip_runtime.h>

typedef unsigned short u16;
typedef float f32x4 __attribute__((ext_vector_type(4)));
typedef __bf16 bf16x8 __attribute__((ext_vector_type(8)));
typedef u16 u16x4 __attribute__((ext_vector_type(4)));
typedef u16 u16x8 __attribute__((ext_vector_type(8)));

#define S_LEN 1024
#define DMODEL 512

__device__ __forceinline__ float bf2f(u16 u) {
    union { unsigned int i; float f; } x; x.i = ((unsigned int)u) << 16; return x.f;
}
__device__ __forceinline__ u16 f2bf(float f) {
    union { float f; unsigned int i; } x; x.f = f;
    unsigned int r = x.i + 0x7fffu + ((x.i >> 16) & 1u);
    return (u16)(r >> 16);
}
__device__ __forceinline__ float load_dual(const void* p, int f32, long idx) {
    return f32 ? ((const float*)p)[idx] : bf2f(((const u16*)p)[idx]);
}
// async global->LDS, 16B/lane; lds base wave-uniform (HW adds lane*16)
__device__ __forceinline__ void load16(const u16* g, u16* lds) {
    __builtin_amdgcn_global_load_lds(
        (const __attribute__((address_space(1))) void*)g,
        (__attribute__((address_space(3))) void*)lds, 16, 0, 0);
}

// ---- dtype detector: fp32 mask words are exactly 0.0f or 1.0f ----
__global__ __launch_bounds__(256) void detect_k(const unsigned int* __restrict__ mw,
                                                int* __restrict__ flag) {
    __shared__ int ok;
    int t = threadIdx.x;
    if (t == 0) ok = 1;
    __syncthreads();
    int bad = 0;
    for (int i = t; i < 4096; i += 256) {
        unsigned int w = mw[i];
        if (w != 0u && w != 0x3F800000u) bad = 1;
    }
    if (bad) ok = 0;
    __syncthreads();
    if (t == 0) flag[0] = ok;   // 1 = fp32 inputs, 0 = bf16
}

__global__ void convert_vec_k(const void* __restrict__ in, const int* __restrict__ flag,
                              u16* __restrict__ out, int n) {
    int i = blockIdx.x * 256 + threadIdx.x;
    if (i < n) out[i] = flag[0] ? f2bf(((const float*)in)[i]) : ((const u16*)in)[i];
}

// LDS-tiled transposing convert: out[c*R+r] = cvt(in[r*C+c]); R,C multiples of 32
__global__ __launch_bounds__(256) void transpose_cvt_k(const void* __restrict__ in,
                                                       const int* __restrict__ flag,
                                                       u16* __restrict__ out, int R, int C) {
    __shared__ u16 tl[32][33];
    int r0 = blockIdx.y << 5, c0 = blockIdx.x << 5;
    int tx = threadIdx.x & 31, ty = threadIdx.x >> 5;
    int f32 = flag[0];
#pragma unroll
    for (int s = 0; s < 4; ++s) {
        int r = r0 + ty + (s << 3);
        tl[ty + (s << 3)][tx] = f2bf(load_dual(in, f32, (long)r * C + c0 + tx));
    }
    __syncthreads();
#pragma unroll
    for (int s = 0; s < 4; ++s) {
        int c = c0 + ty + (s << 3);
        out[(long)c * R + r0 + tx] = tl[tx][ty + (s << 3)];
    }
}

__global__ void convert_x_k(const void* __restrict__ xin, const int* __restrict__ flag,
                            u16* __restrict__ xb, float* __restrict__ xc, int n) {
    int i = blockIdx.x * 256 + threadIdx.x;
    if (i < n) {
        float v = load_dual(xin, flag[0], i);
        xb[i] = f2bf(v);
        xc[i] = v;
    }
}

__global__ __launch_bounds__(256) void count_k(const int* __restrict__ p, float* __restrict__ out) {
    __shared__ int r4[4];
    int t = threadIdx.x;
    int c = 0;
    for (int i = t; i < 1024; i += 256) c += (p[i] != 0) ? 1 : 0;
    for (int off = 32; off; off >>= 1) c += __shfl_xor(c, off);
    if ((t & 63) == 0) r4[t >> 6] = c;
    __syncthreads();
    if (t == 0) out[0] = (float)(r4[0] + r4[1] + r4[2] + r4[3]);
}

enum { G_QKV = 0, G_RELU = 1 };

// 128x128 tile, BK=32, 4 waves (64x64 quadrants, 4x4 frags), global_load_lds staging.
template <int MODE>
__global__ __launch_bounds__(256) void gemm128(
    const u16* __restrict__ A, int lda,
    const u16* __restrict__ Bt, int ldb,
    int K, const u16* __restrict__ bias,
    void* __restrict__ out0, int ldc,
    u16* __restrict__ out1, u16* __restrict__ out2)
{
    __shared__ __align__(16) u16 As[128 * 32];
    __shared__ __align__(16) u16 Bs[128 * 32];
    const int tid = threadIdx.x, w = tid >> 6, l = tid & 63;
    const int quad = l >> 4, l16 = l & 15;
    const int bm = blockIdx.x * 128, bn = blockIdx.y * 128;
    const int srow = tid >> 2, scol = (tid & 3) << 3;
    const int mw = (w >> 1) << 6, nw = (w & 1) << 6;
    f32x4 acc[4][4] = {};

    for (int k0 = 0; k0 < K; k0 += 32) {
        load16(A + (long)(bm + srow) * lda + (k0 + scol),       As + (w << 9));
        load16(A + (long)(bm + 64 + srow) * lda + (k0 + scol),  As + 2048 + (w << 9));
        load16(Bt + (long)(bn + srow) * ldb + (k0 + scol),      Bs + (w << 9));
        load16(Bt + (long)(bn + 64 + srow) * ldb + (k0 + scol), Bs + 2048 + (w << 9));
        __syncthreads();
        bf16x8 a[4], b[4];
#pragma unroll
        for (int i = 0; i < 4; ++i) {
            a[i] = *(const bf16x8*)(As + (mw + (i << 4) + l16) * 32 + (quad << 3));
            b[i] = *(const bf16x8*)(Bs + (nw + (i << 4) + l16) * 32 + (quad << 3));
        }
#pragma unroll
        for (int mi = 0; mi < 4; ++mi)
#pragma unroll
            for (int ni = 0; ni < 4; ++ni)
                acc[mi][ni] = __builtin_amdgcn_mfma_f32_16x16x32_bf16(a[mi], b[ni], acc[mi][ni], 0, 0, 0);
        __syncthreads();
    }

    if constexpr (MODE == G_QKV) {
        u16* qb = (u16*)out0;
#pragma unroll
        for (int ni = 0; ni < 4; ++ni) {
            int col = bn + nw + (ni << 4) + l16;
            float bv = bf2f(bias[col]);
            if (col < 1024) {
                u16* dst = (col < 512) ? qb : out1;
                int cc = col & 511;
#pragma unroll
                for (int mi = 0; mi < 4; ++mi) {
                    int rowb = bm + mw + (mi << 4) + (quad << 2);
#pragma unroll
                    for (int r = 0; r < 4; ++r)
                        dst[(long)(rowb + r) * 512 + cc] = f2bf(acc[mi][ni][r] + bv);
                }
            } else {
                int h = (col - 1024) >> 6, d = col & 63;
#pragma unroll
                for (int mi = 0; mi < 4; ++mi) {
                    int rowb = bm + mw + (mi << 4) + (quad << 2);
                    int b_ = rowb >> 10, ii = rowb & 1023;
                    u16x4 pk;
#pragma unroll
                    for (int r = 0; r < 4; ++r) pk[r] = f2bf(acc[mi][ni][r] + bv);
                    *(u16x4*)(out2 + ((((long)b_ * 8 + h) * 64 + d) << 10) + ii) = pk;
                }
            }
        }
    } else {
        u16* o = (u16*)out0;
#pragma unroll
        for (int ni = 0; ni < 4; ++ni) {
            int col = bn + nw + (ni << 4) + l16;
            float bv = bf2f(bias[col]);
#pragma unroll
            for (int mi = 0; mi < 4; ++mi) {
                int rowb = bm + mw + (mi << 4) + (quad << 2);
#pragma unroll
                for (int r = 0; r < 4; ++r)
                    o[(long)(rowb + r) * ldc + col] = f2bf(fmaxf(acc[mi][ni][r] + bv, 0.0f));
            }
        }
    }
}

// 64x128 tile RES GEMM (C = A*Bt^T + bias + resid, fp32 out) — 256-block grids for N=512
__global__ __launch_bounds__(256) void gemm_rw(
    const u16* __restrict__ A, int lda,
    const u16* __restrict__ Bt, int ldb,
    int K, const u16* __restrict__ bias,
    float* __restrict__ out0, int ldc,
    const float* __restrict__ resid)
{
    __shared__ __align__(16) u16 As[64 * 32];
    __shared__ __align__(16) u16 Bs[128 * 32];
    const int tid = threadIdx.x, w = tid >> 6, l = tid & 63;
    const int quad = l >> 4, l16 = l & 15;
    const int bm = blockIdx.x * 64, bn = blockIdx.y * 128;
    const int srow = tid >> 2, scol = (tid & 3) << 3;
    const int mwv = (w >> 1) << 5, nwv = (w & 1) << 6;
    f32x4 acc[2][4] = {};

    for (int k0 = 0; k0 < K; k0 += 32) {
        load16(A + (long)(bm + srow) * lda + (k0 + scol),       As + (w << 9));
        load16(Bt + (long)(bn + srow) * ldb + (k0 + scol),      Bs + (w << 9));
        load16(Bt + (long)(bn + 64 + srow) * ldb + (k0 + scol), Bs + 2048 + (w << 9));
        __syncthreads();
        bf16x8 a[2], b[4];
#pragma unroll
        for (int i = 0; i < 2; ++i)
            a[i] = *(const bf16x8*)(As + (mwv + (i << 4) + l16) * 32 + (quad << 3));
#pragma unroll
        for (int i = 0; i < 4; ++i)
            b[i] = *(const bf16x8*)(Bs + (nwv + (i << 4) + l16) * 32 + (quad << 3));
#pragma unroll
        for (int mi = 0; mi < 2; ++mi)
#pragma unroll
            for (int ni = 0; ni < 4; ++ni)
                acc[mi][ni] = __builtin_amdgcn_mfma_f32_16x16x32_bf16(a[mi], b[ni], acc[mi][ni], 0, 0, 0);
        __syncthreads();
    }
#pragma unroll
    for (int ni = 0; ni < 4; ++ni) {
        int col = bn + nwv + (ni << 4) + l16;
        float bv = bf2f(bias[col]);
#pragma unroll
        for (int mi = 0; mi < 2; ++mi) {
            int rowb = bm + mwv + (mi << 4) + (quad << 2);
#pragma unroll
            for (int r = 0; r < 4; ++r) {
                long row = rowb + r;
                out0[row * ldc + col] = acc[mi][ni][r] + bv + resid[row * DMODEL + col];
            }
        }
    }
}

// Fused attention: per (z, j-tile) compute exp(QK^T+mask) and accumulate S^T V,
// unnormalized. Emits per-tile exp-sums; optionally spills raw exp [i][j] (layer 3).
__global__ __launch_bounds__(256) void attn_flash(
    const u16* __restrict__ qb, const u16* __restrict__ kb, const u16* __restrict__ vT,
    const void* __restrict__ maskp, const int* __restrict__ dflag,
    u16* __restrict__ attn_u, float* __restrict__ partials, u16* __restrict__ rawexp)
{
    __shared__ __align__(16) u16 KtA[2048], KtB[2048];
    __shared__ __align__(16) u16 QtA[2048], QtB[2048];
    __shared__ __align__(16) u16 VlA[2048], VlB[2048];
    __shared__ __align__(16) u16 Sl[64 * 72];
    __shared__ float redp[4];
    const int tid = threadIdx.x, w = tid >> 6, l = tid & 63;
    const int q4 = l >> 4, l16 = l & 15;
    const int z = blockIdx.y, zb = z >> 3, zh = z & 7;
    const int j0 = blockIdx.x << 6;
    const u16* Q = qb + (long)zb * 524288 + zh * 64;
    const u16* K = kb + (long)zb * 524288 + zh * 64;
    const u16* V = vT + (long)z * 65536;
    const int f32m = dflag[0];
    const int srow = tid >> 2, scol = (tid & 3) << 3;
    const int swz = (l16 & 7) << 3;   // S LDS xor-swizzle (row-dependent)

    load16(K + (long)(j0 + srow) * 512 + scol,      KtA + (w << 9));
    load16(K + (long)(j0 + srow) * 512 + 32 + scol, KtB + (w << 9));
    __syncthreads();
    bf16x8 b1A[4], b1B[4];
#pragma unroll
    for (int c = 0; c < 4; ++c) {
        b1A[c] = *(const bf16x8*)(KtA + ((c << 4) + l16) * 32 + (q4 << 3));
        b1B[c] = *(const bf16x8*)(KtB + ((c << 4) + l16) * 32 + (q4 << 3));
    }
    f32x4 acc2[4] = {};
    float lsum = 0.0f;

    for (int ib = 0; ib < 1024; ib += 64) {
        __syncthreads();   // prev iter done reading Qt/Vl
        load16(Q + (long)(ib + srow) * 512 + scol,       QtA + (w << 9));
        load16(Q + (long)(ib + srow) * 512 + 32 + scol,  QtB + (w << 9));
        load16(V + (long)srow * 1024 + ib + scol,        VlA + (w << 9));
        load16(V + (long)srow * 1024 + ib + 32 + scol,   VlB + (w << 9));
        __syncthreads();   // staging complete
        bf16x8 a1A = *(const bf16x8*)(QtA + ((w << 4) + l16) * 32 + (q4 << 3));
        bf16x8 a1B = *(const bf16x8*)(QtB + ((w << 4) + l16) * 32 + (q4 << 3));
        f32x4 acc1[4] = {};
#pragma unroll
        for (int c = 0; c < 4; ++c) {
            acc1[c] = __builtin_amdgcn_mfma_f32_16x16x32_bf16(a1A, b1A[c], acc1[c], 0, 0, 0);
            acc1[c] = __builtin_amdgcn_mfma_f32_16x16x32_bf16(a1B, b1B[c], acc1[c], 0, 0, 0);
        }
        // epilogue: mask + exp; write S^T to LDS (swizzled)
#pragma unroll
        for (int c = 0; c < 4; ++c) {
            int j = (c << 4) + l16;       // local j
            u16x4 pk;
#pragma unroll
            for (int r = 0; r < 4; ++r) {
                int i = ib + (w << 4) + (q4 << 2) + r;     // global i
                float mv = load_dual(maskp, f32m,
                                     (long)zb * 1048576 + (long)i * 1024 + j0 + j);
                float e = __expf((acc1[c][r] + mv * (-1e9f)) * 0.125f);
                lsum += e;
                pk[r] = f2bf(e);
                if (rawexp)
                    rawexp[(long)z * 1048576 + (long)i * 1024 + j0 + j] = pk[r];
            }
            *(u16x4*)(Sl + j * 72 + ((((w << 4) + (q4 << 2)) ^ swz))) = pk;
        }
        __syncthreads();   // Sl ready
        bf16x8 a2A = *(const bf16x8*)(Sl + ((w << 4) + l16) * 72 + (((q4 << 3)) ^ swz));
        bf16x8 a2B = *(const bf16x8*)(Sl + ((w << 4) + l16) * 72 + ((32 + (q4 << 3)) ^ swz));
#pragma unroll
        for (int c = 0; c < 4; ++c) {
            bf16x8 b2A = *(const bf16x8*)(VlA + (((c << 4) + l16) << 5) + (q4 << 3));
            acc2[c] = __builtin_amdgcn_mfma_f32_16x16x32_bf16(a2A, b2A, acc2[c], 0, 0, 0);
            bf16x8 b2B = *(const bf16x8*)(VlB + (((c << 4) + l16) << 5) + (q4 << 3));
            acc2[c] = __builtin_amdgcn_mfma_f32_16x16x32_bf16(a2B, b2B, acc2[c], 0, 0, 0);
        }
    }
    // write unnormalized attn[b][j][h*64+d]
#pragma unroll
    for (int c = 0; c < 4; ++c) {
        int d = (c << 4) + l16;
#pragma unroll
        for (int r = 0; r < 4; ++r) {
            int jg = j0 + (w << 4) + (q4 << 2) + r;
            attn_u[(long)zb * 524288 + (long)jg * 512 + zh * 64 + d] = f2bf(acc2[c][r]);
        }
    }
    for (int off = 32; off; off >>= 1) lsum += __shfl_xor(lsum, off);
    if (l == 0) redp[w] = lsum;
    __syncthreads();
    if (tid == 0)
        partials[z * 16 + blockIdx.x] = redp[0] + redp[1] + redp[2] + redp[3];
}

__global__ __launch_bounds__(64) void merge16(const float* __restrict__ partials,
                                              float* __restrict__ stats,
                                              const float* __restrict__ rowc) {
    int z = blockIdx.x, t = threadIdx.x;
    float s = (t < 16) ? partials[z * 16 + t] : 0.0f;
    for (int off = 8; off; off >>= 1) s += __shfl_xor(s, off);
    if (t == 0) stats[z] = rowc[0] / fmaxf(s, 1e-30f);
}

__global__ __launch_bounds__(256) void scale_attn(u16* __restrict__ attn,
                                                  const float* __restrict__ stats) {
    int idx8 = blockIdx.x * 256 + threadIdx.x;          // 262144 chunks
    long base = (long)idx8 * 8;
    int zz = (int)(base >> 19) * 8 + (int)((base >> 6) & 7);
    float sc = stats[zz];
    u16x8 v = *(u16x8*)(attn + base);
#pragma unroll
    for (int e = 0; e < 8; ++e) v[e] = f2bf(bf2f(v[e]) * sc);
    *(u16x8*)(attn + base) = v;
}

__global__ __launch_bounds__(256) void aw_out_k(const u16* __restrict__ raw,
                                                const float* __restrict__ stats,
                                                void* __restrict__ dout,
                                                const int* __restrict__ dflag) {
    int idx8 = blockIdx.x * 256 + threadIdx.x;          // 4194304 chunks
    long base = (long)idx8 * 8;
    float sc = stats[(int)(base >> 20)];
    u16x8 v = *(const u16x8*)(raw + base);
    if (dflag[0]) {
        float* o = (float*)dout + 2097152 + base;
#pragma unroll
        for (int e = 0; e < 8; ++e) o[e] = bf2f(v[e]) * sc;
    } else {
        u16x8 r;
#pragma unroll
        for (int e = 0; e < 8; ++e) r[e] = f2bf(bf2f(v[e]) * sc);
        *(u16x8*)((u16*)dout + 2097152 + base) = r;
    }
}

__global__ __launch_bounds__(256) void layernorm_k(const float* __restrict__ in,
                                                   const u16* __restrict__ g,
                                                   const u16* __restrict__ bb,
                                                   float* __restrict__ outf,
                                                   void* __restrict__ outb,
                                                   const int* __restrict__ of) {
    __shared__ float red[8];
    int row = blockIdx.x, t = threadIdx.x, wave = t >> 6, lane = t & 63;
    const float* x = in + (long)row * DMODEL;
    float v0 = x[t], v1 = x[t + 256];
    float s = v0 + v1;
    for (int off = 32; off; off >>= 1) s += __shfl_xor(s, off);
    if (lane == 0) red[wave] = s;
    __syncthreads();
    float mean = (red[0] + red[1] + red[2] + red[3]) * (1.0f / 512.0f);
    float d0 = v0 - mean, d1 = v1 - mean;
    float q = d0 * d0 + d1 * d1;
    for (int off = 32; off; off >>= 1) q += __shfl_xor(q, off);
    if (lane == 0) red[4 + wave] = q;
    __syncthreads();
    float var = (red[4] + red[5] + red[6] + red[7]) * (1.0f / 512.0f);
    float inv = rsqrtf(var + 1e-9f);
    float o0 = bf2f(g[t]) * d0 * inv + bf2f(bb[t]);
    float o1 = bf2f(g[t + 256]) * d1 * inv + bf2f(bb[t + 256]);
    long base = (long)row * DMODEL;
    if (outf) { outf[base + t] = o0; outf[base + t + 256] = o1; }
    if (of && of[0]) {
        ((float*)outb)[base + t] = o0;
        ((float*)outb)[base + t + 256] = o1;
    } else {
        ((u16*)outb)[base + t] = f2bf(o0);
        ((u16*)outb)[base + t + 256] = f2bf(o1);
    }
}

extern "C" void kernel_launch(void* const* d_in, const int* in_sizes, int n_in,
                              void* d_out, int out_size, void* d_ws, size_t ws_size,
                              hipStream_t stream) {
    const void* x_in   = d_in[0];
    const void* maskr  = d_in[1];
    const int*  protok = (const int*)d_in[2];
    const void* wq_w = d_in[3];  const void* wq_b = d_in[4];
    const void* wk_w = d_in[5];  const void* wk_b = d_in[6];
    const void* wv_w = d_in[7];  const void* wv_b = d_in[8];
    const void* wo_w = d_in[9];  const void* wo_b = d_in[10];
    const void* w1   = d_in[11]; const void* b1   = d_in[12];
    const void* w2   = d_in[13]; const void* b2   = d_in[14];
    const void* ln1g = d_in[15]; const void* ln1b = d_in[16];
    const void* ln2g = d_in[17]; const void* ln2b = d_in[18];

    char* p = (char*)d_ws;
    auto alloc = [&](size_t bytes) { char* r = p; p += (bytes + 255) & ~(size_t)255; return (void*)r; };

    u16* wqkvT = (u16*)alloc((size_t)1536 * 512 * 2);
    u16* woT   = (u16*)alloc(512 * 512 * 2);
    u16* w1T   = (u16*)alloc((size_t)512 * 2048 * 2);
    u16* w2T   = (u16*)alloc((size_t)2048 * 512 * 2);
    u16* qb    = (u16*)alloc((size_t)4096 * 512 * 2);
    u16* kb    = (u16*)alloc((size_t)4096 * 512 * 2);
    u16* vT    = (u16*)alloc((size_t)32 * 64 * 1024 * 2);
    u16* attn  = (u16*)alloc((size_t)4096 * 512 * 2);
    u16* rawE  = (u16*)alloc((size_t)32 * 1024 * 1024 * 2);   // layer-3 raw exp
    float* xcur  = (float*)alloc((size_t)4096 * 512 * 4);
    u16*   xbf   = (u16*)alloc((size_t)4096 * 512 * 2);
    float* resb  = (float*)alloc((size_t)4096 * 512 * 4);
    float* out1f = (float*)alloc((size_t)4096 * 512 * 4);
    u16*   out1b = (u16*)alloc((size_t)4096 * 512 * 2);
    u16*   ffnh  = (u16*)alloc((size_t)4096 * 2048 * 2);
    float* partials = (float*)alloc(32 * 16 * 4);
    float* stats    = (float*)alloc(32 * 4);
    float* rowc     = (float*)alloc(256);
    u16*   barena   = (u16*)alloc(8192 * 2);
    int*   dflag    = (int*)alloc(256);

    if ((size_t)(p - (char*)d_ws) > ws_size) return;

    detect_k<<<1, 256, 0, stream>>>((const unsigned int*)maskr, dflag);

    transpose_cvt_k<<<dim3(16, 16), 256, 0, stream>>>(wq_w, dflag, wqkvT, 512, 512);
    transpose_cvt_k<<<dim3(16, 16), 256, 0, stream>>>(wk_w, dflag, wqkvT + 512 * 512, 512, 512);
    transpose_cvt_k<<<dim3(16, 16), 256, 0, stream>>>(wv_w, dflag, wqkvT + 1024 * 512, 512, 512);
    transpose_cvt_k<<<dim3(16, 16), 256, 0, stream>>>(wo_w, dflag, woT, 512, 512);
    transpose_cvt_k<<<dim3(64, 16), 256, 0, stream>>>(w1, dflag, w1T, 512, 2048);
    transpose_cvt_k<<<dim3(16, 64), 256, 0, stream>>>(w2, dflag, w2T, 2048, 512);

    convert_vec_k<<<2, 256, 0, stream>>>(wq_b, dflag, barena + 0, 512);
    convert_vec_k<<<2, 256, 0, stream>>>(wk_b, dflag, barena + 512, 512);
    convert_vec_k<<<2, 256, 0, stream>>>(wv_b, dflag, barena + 1024, 512);
    convert_vec_k<<<2, 256, 0, stream>>>(wo_b, dflag, barena + 1536, 512);
    convert_vec_k<<<8, 256, 0, stream>>>(b1, dflag, barena + 2048, 2048);
    convert_vec_k<<<2, 256, 0, stream>>>(b2, dflag, barena + 4096, 512);
    convert_vec_k<<<2, 256, 0, stream>>>(ln1g, dflag, barena + 4608, 512);
    convert_vec_k<<<2, 256, 0, stream>>>(ln1b, dflag, barena + 5120, 512);
    convert_vec_k<<<2, 256, 0, stream>>>(ln2g, dflag, barena + 5632, 512);
    convert_vec_k<<<2, 256, 0, stream>>>(ln2b, dflag, barena + 6144, 512);

    count_k<<<1, 256, 0, stream>>>(protok, rowc);
    convert_x_k<<<8192, 256, 0, stream>>>(x_in, dflag, xbf, xcur, 2097152);

    for (int layer = 0; layer < 4; ++layer) {
        gemm128<G_QKV><<<dim3(32, 12), 256, 0, stream>>>(
            xbf, 512, wqkvT, 512, 512, barena + 0, qb, 512, kb, vT);
        attn_flash<<<dim3(16, 32), 256, 0, stream>>>(
            qb, kb, vT, maskr, dflag, attn, partials,
            (layer == 3) ? rawE : nullptr);
        merge16<<<32, 64, 0, stream>>>(partials, stats, rowc);
        scale_attn<<<1024, 256, 0, stream>>>(attn, stats);
        if (layer == 3)
            aw_out_k<<<16384, 256, 0, stream>>>(rawE, stats, d_out, dflag);
        gemm_rw<<<dim3(64, 4), 256, 0, stream>>>(
            attn, 512, woT, 512, 512, barena + 1536, resb, 512, xcur);
        layernorm_k<<<4096, 256, 0, stream>>>(resb, barena + 4608, barena + 5120,
                                              out1f, out1b, nullptr);
        gemm128<G_RELU><<<dim3(32, 16), 256, 0, stream>>>(
            out1b, 512, w1T, 512, 512, barena + 2048, ffnh, 2048, nullptr, nullptr);
        gemm_rw<<<dim3(64, 4), 256, 0, stream>>>(
            ffnh, 2048, w2T, 2048, 2048, barena + 4096, resb, 512, out1f);
        layernorm_k<<<4096, 256, 0, stream>>>(resb, barena + 5632, barena + 6144,
                                              xcur, (layer == 3) ? d_out : (void*)xbf,
                                              (layer == 3) ? dflag : nullptr);
    }
}

// Round 6
// 765.054 us; speedup vs baseline: 1.3052x; 1.3052x over previous
//
#include <hip/hip_runtime.h>

typedef unsigned short u16;
typedef float f32x4 __attribute__((ext_vector_type(4)));
typedef __bf16 bf16x8 __attribute__((ext_vector_type(8)));
typedef u16 u16x4 __attribute__((ext_vector_type(4)));

#define S_LEN 1024
#define DMODEL 512

__device__ __forceinline__ float bf2f(u16 u) {
    union { unsigned int i; float f; } x; x.i = ((unsigned int)u) << 16; return x.f;
}
__device__ __forceinline__ u16 f2bf(float f) {
    union { float f; unsigned int i; } x; x.f = f;
    unsigned int r = x.i + 0x7fffu + ((x.i >> 16) & 1u);
    return (u16)(r >> 16);
}
__device__ __forceinline__ float load_dual(const void* p, int f32, long idx) {
    return f32 ? ((const float*)p)[idx] : bf2f(((const u16*)p)[idx]);
}
// async global->LDS, 16B/lane; lds base wave-uniform (HW adds lane*16)
__device__ __forceinline__ void load16(const u16* g, u16* lds) {
    __builtin_amdgcn_global_load_lds(
        (const __attribute__((address_space(1))) void*)g,
        (__attribute__((address_space(3))) void*)lds, 16, 0, 0);
}

// ---- dtype detector: fp32 mask words are exactly 0.0f or 1.0f ----
__global__ __launch_bounds__(256) void detect_k(const unsigned int* __restrict__ mw,
                                                int* __restrict__ flag) {
    __shared__ int ok;
    int t = threadIdx.x;
    if (t == 0) ok = 1;
    __syncthreads();
    int bad = 0;
    for (int i = t; i < 4096; i += 256) {
        unsigned int w = mw[i];
        if (w != 0u && w != 0x3F800000u) bad = 1;
    }
    if (bad) ok = 0;
    __syncthreads();
    if (t == 0) flag[0] = ok;   // 1 = fp32 inputs, 0 = bf16
}

// One kernel for all setup: weight transposes, bias/LN converts, row count,
// mask->mz vector, x convert. Branch by blockIdx range.
__global__ __launch_bounds__(256) void mega_setup(
    const void* __restrict__ wq_w, const void* __restrict__ wk_w,
    const void* __restrict__ wv_w, const void* __restrict__ wo_w,
    const void* __restrict__ w1, const void* __restrict__ w2,
    const void* __restrict__ wq_b, const void* __restrict__ wk_b,
    const void* __restrict__ wv_b, const void* __restrict__ wo_b,
    const void* __restrict__ b1, const void* __restrict__ b2,
    const void* __restrict__ ln1g, const void* __restrict__ ln1b,
    const void* __restrict__ ln2g, const void* __restrict__ ln2b,
    const int* __restrict__ protok, const void* __restrict__ maskr,
    const void* __restrict__ x_in, const int* __restrict__ flag,
    u16* __restrict__ wqkvT, u16* __restrict__ woT,
    u16* __restrict__ w1T, u16* __restrict__ w2T,
    u16* __restrict__ barena, float* __restrict__ rowc,
    float* __restrict__ mzf, u16* __restrict__ xbf, float* __restrict__ xcur)
{
    __shared__ u16 tl[32][33];
    __shared__ int r4[4];
    const int bid = blockIdx.x, t = threadIdx.x;
    const int f32 = flag[0];
    if (bid < 3072) {           // 32x32 transpose tiles
        const void* in; u16* out; int R, C, tile;
        if (bid < 256)       { in = wq_w; out = wqkvT;              R = 512;  C = 512;  tile = bid; }
        else if (bid < 512)  { in = wk_w; out = wqkvT + 512 * 512;  R = 512;  C = 512;  tile = bid - 256; }
        else if (bid < 768)  { in = wv_w; out = wqkvT + 1024 * 512; R = 512;  C = 512;  tile = bid - 512; }
        else if (bid < 1024) { in = wo_w; out = woT;                R = 512;  C = 512;  tile = bid - 768; }
        else if (bid < 2048) { in = w1;   out = w1T;                R = 512;  C = 2048; tile = bid - 1024; }
        else                 { in = w2;   out = w2T;                R = 2048; C = 512;  tile = bid - 2048; }
        int tilesX = C >> 5;
        int r0 = (tile / tilesX) << 5, c0 = (tile % tilesX) << 5;
        int tx = t & 31, ty = t >> 5;
#pragma unroll
        for (int s = 0; s < 4; ++s) {
            int r = r0 + ty + (s << 3);
            tl[ty + (s << 3)][tx] = f2bf(load_dual(in, f32, (long)r * C + c0 + tx));
        }
        __syncthreads();
#pragma unroll
        for (int s = 0; s < 4; ++s) {
            int c = c0 + ty + (s << 3);
            out[(long)c * R + r0 + tx] = tl[tx][ty + (s << 3)];
        }
    } else if (bid < 3082) {    // bias / LN param converts into barena
        int a = bid - 3072;
        const void* src; int off, n;
        switch (a) {
            case 0:  src = wq_b; off = 0;    n = 512;  break;
            case 1:  src = wk_b; off = 512;  n = 512;  break;
            case 2:  src = wv_b; off = 1024; n = 512;  break;
            case 3:  src = wo_b; off = 1536; n = 512;  break;
            case 4:  src = b1;   off = 2048; n = 2048; break;
            case 5:  src = b2;   off = 4096; n = 512;  break;
            case 6:  src = ln1g; off = 4608; n = 512;  break;
            case 7:  src = ln1b; off = 5120; n = 512;  break;
            case 8:  src = ln2g; off = 5632; n = 512;  break;
            default: src = ln2b; off = 6144; n = 512;  break;
        }
        for (int i = t; i < n; i += 256)
            barena[off + i] = f2bf(load_dual(src, f32, i));
    } else if (bid == 3082) {   // row count
        int c = 0;
        for (int i = t; i < 1024; i += 256) c += (protok[i] != 0) ? 1 : 0;
        for (int off = 32; off; off >>= 1) c += __shfl_xor(c, off);
        if ((t & 63) == 0) r4[t >> 6] = c;
        __syncthreads();
        if (t == 0) rowc[0] = (float)(r4[0] + r4[1] + r4[2] + r4[3]);
    } else if (bid < 3087) {    // mz[b][j] = masked? 0 : 1 (mask is pad[b,j] broadcast over i)
        int b = bid - 3083;
        for (int j = t; j < 1024; j += 256) {
            float mv = load_dual(maskr, f32, (long)b * 1048576 + j);
            mzf[(b << 10) + j] = (mv != 0.0f) ? 0.0f : 1.0f;
        }
    } else {                    // x convert: 1024 blocks x 2048 elems
        long base = (long)(bid - 3087) * 2048;
        for (int i = t; i < 2048; i += 256) {
            float v = load_dual(x_in, f32, base + i);
            xbf[base + i] = f2bf(v);
            xcur[base + i] = v;
        }
    }
}

enum { G_QKV = 0, G_RELU = 1 };

// 128x128 tile, BK=32, 4 waves (64x64 quadrants, 4x4 frags), global_load_lds staging.
template <int MODE>
__global__ __launch_bounds__(256) void gemm128(
    const u16* __restrict__ A, int lda,
    const u16* __restrict__ Bt, int ldb,
    int K, const u16* __restrict__ bias,
    void* __restrict__ out0, int ldc,
    u16* __restrict__ out1, u16* __restrict__ out2)
{
    __shared__ __align__(16) u16 As[128 * 32];
    __shared__ __align__(16) u16 Bs[128 * 32];
    const int tid = threadIdx.x, w = tid >> 6, l = tid & 63;
    const int quad = l >> 4, l16 = l & 15;
    const int bm = blockIdx.x * 128, bn = blockIdx.y * 128;
    const int srow = tid >> 2, scol = (tid & 3) << 3;
    const int mw = (w >> 1) << 6, nw = (w & 1) << 6;
    f32x4 acc[4][4] = {};

    for (int k0 = 0; k0 < K; k0 += 32) {
        load16(A + (long)(bm + srow) * lda + (k0 + scol),       As + (w << 9));
        load16(A + (long)(bm + 64 + srow) * lda + (k0 + scol),  As + 2048 + (w << 9));
        load16(Bt + (long)(bn + srow) * ldb + (k0 + scol),      Bs + (w << 9));
        load16(Bt + (long)(bn + 64 + srow) * ldb + (k0 + scol), Bs + 2048 + (w << 9));
        __syncthreads();
        bf16x8 a[4], b[4];
#pragma unroll
        for (int i = 0; i < 4; ++i) {
            a[i] = *(const bf16x8*)(As + (mw + (i << 4) + l16) * 32 + (quad << 3));
            b[i] = *(const bf16x8*)(Bs + (nw + (i << 4) + l16) * 32 + (quad << 3));
        }
#pragma unroll
        for (int mi = 0; mi < 4; ++mi)
#pragma unroll
            for (int ni = 0; ni < 4; ++ni)
                acc[mi][ni] = __builtin_amdgcn_mfma_f32_16x16x32_bf16(a[mi], b[ni], acc[mi][ni], 0, 0, 0);
        __syncthreads();
    }

    if constexpr (MODE == G_QKV) {
        u16* qb = (u16*)out0;
#pragma unroll
        for (int ni = 0; ni < 4; ++ni) {
            int col = bn + nw + (ni << 4) + l16;
            float bv = bf2f(bias[col]);
            if (col < 1024) {
                u16* dst = (col < 512) ? qb : out1;
                int cc = col & 511;
#pragma unroll
                for (int mi = 0; mi < 4; ++mi) {
                    int rowb = bm + mw + (mi << 4) + (quad << 2);
#pragma unroll
                    for (int r = 0; r < 4; ++r)
                        dst[(long)(rowb + r) * 512 + cc] = f2bf(acc[mi][ni][r] + bv);
                }
            } else {
                int h = (col - 1024) >> 6, d = col & 63;
#pragma unroll
                for (int mi = 0; mi < 4; ++mi) {
                    int rowb = bm + mw + (mi << 4) + (quad << 2);
                    int b_ = rowb >> 10, ii = rowb & 1023;
                    u16x4 pk;
#pragma unroll
                    for (int r = 0; r < 4; ++r) pk[r] = f2bf(acc[mi][ni][r] + bv);
                    *(u16x4*)(out2 + ((((long)b_ * 8 + h) * 64 + d) << 10) + ii) = pk;
                }
            }
        }
    } else {
        u16* o = (u16*)out0;
#pragma unroll
        for (int ni = 0; ni < 4; ++ni) {
            int col = bn + nw + (ni << 4) + l16;
            float bv = bf2f(bias[col]);
#pragma unroll
            for (int mi = 0; mi < 4; ++mi) {
                int rowb = bm + mw + (mi << 4) + (quad << 2);
#pragma unroll
                for (int r = 0; r < 4; ++r)
                    o[(long)(rowb + r) * ldc + col] = f2bf(fmaxf(acc[mi][ni][r] + bv, 0.0f));
            }
        }
    }
}

// QK^T + exp + mask-zero, writing awT[j][i] (TN layout for PV). D[j,i] = K_j . Q_i.
__global__ __launch_bounds__(256) void qk_exp(
    const u16* __restrict__ kb, const u16* __restrict__ qb,
    const float* __restrict__ mzf,
    u16* __restrict__ awT, float* __restrict__ partials)
{
    __shared__ __align__(16) u16 As[128 * 32];
    __shared__ __align__(16) u16 Bs[128 * 32];
    __shared__ float redp[4];
    const int tid = threadIdx.x, w = tid >> 6, l = tid & 63;
    const int quad = l >> 4, l16 = l & 15;
    const int bm = blockIdx.x * 128, bn = blockIdx.y * 128;   // bm = j, bn = i
    const int z = blockIdx.z, zb = z >> 3, zh = z & 7;
    const u16* A = kb + (long)zb * 524288 + zh * 64;
    const u16* B = qb + (long)zb * 524288 + zh * 64;
    const int srow = tid >> 2, scol = (tid & 3) << 3;
    const int mw = (w >> 1) << 6, nw = (w & 1) << 6;
    f32x4 acc[4][4] = {};

    for (int k0 = 0; k0 < 64; k0 += 32) {
        load16(A + (long)(bm + srow) * 512 + (k0 + scol),       As + (w << 9));
        load16(A + (long)(bm + 64 + srow) * 512 + (k0 + scol),  As + 2048 + (w << 9));
        load16(B + (long)(bn + srow) * 512 + (k0 + scol),       Bs + (w << 9));
        load16(B + (long)(bn + 64 + srow) * 512 + (k0 + scol),  Bs + 2048 + (w << 9));
        __syncthreads();
        bf16x8 a[4], b[4];
#pragma unroll
        for (int i = 0; i < 4; ++i) {
            a[i] = *(const bf16x8*)(As + (mw + (i << 4) + l16) * 32 + (quad << 3));
            b[i] = *(const bf16x8*)(Bs + (nw + (i << 4) + l16) * 32 + (quad << 3));
        }
#pragma unroll
        for (int mi = 0; mi < 4; ++mi)
#pragma unroll
            for (int ni = 0; ni < 4; ++ni)
                acc[mi][ni] = __builtin_amdgcn_mfma_f32_16x16x32_bf16(a[mi], b[ni], acc[mi][ni], 0, 0, 0);
        __syncthreads();
    }

    float lsum = 0.0f;
    u16* awz = awT + (long)z * 1048576;
#pragma unroll
    for (int mi = 0; mi < 4; ++mi) {
        int jb = bm + mw + (mi << 4) + (quad << 2);
        f32x4 mzv = *(const f32x4*)(mzf + (zb << 10) + jb);
#pragma unroll
        for (int ni = 0; ni < 4; ++ni) {
            int ic = bn + nw + (ni << 4) + l16;
#pragma unroll
            for (int r = 0; r < 4; ++r) {
                float e = __expf(acc[mi][ni][r] * 0.125f) * mzv[r];
                lsum += e;
                awz[(long)(jb + r) * 1024 + ic] = f2bf(e);
            }
        }
    }
    for (int off = 32; off; off >>= 1) lsum += __shfl_xor(lsum, off);
    if (l == 0) redp[w] = lsum;
    __syncthreads();
    if (tid == 0)
        partials[(z << 6) + (blockIdx.y << 3) + blockIdx.x] =
            redp[0] + redp[1] + redp[2] + redp[3];
}

__global__ __launch_bounds__(64) void merge64(const float* __restrict__ partials,
                                              float* __restrict__ stats,
                                              const float* __restrict__ rowc) {
    int z = blockIdx.x, t = threadIdx.x;
    float s = partials[(z << 6) + t];
    for (int off = 32; off; off >>= 1) s += __shfl_xor(s, off);
    if (t == 0) stats[z] = rowc[0] / fmaxf(s, 1e-30f);
}

// PV: attn[j,d] = sc * sum_i awT[j,i]*vT[d,i]; 64x64 tile TN, lds-async staging.
__global__ __launch_bounds__(256) void gemm_pv(const u16* __restrict__ awT,
                                               const u16* __restrict__ vT,
                                               const float* __restrict__ stats,
                                               u16* __restrict__ attn)
{
    __shared__ __align__(16) u16 As[64 * 32];
    __shared__ __align__(16) u16 Bs[64 * 32];
    const int tid = threadIdx.x, w = tid >> 6, l = tid & 63;
    const int quad = l >> 4, l16 = l & 15;
    const int bm = blockIdx.x * 64;
    const int z = blockIdx.y, zb = z >> 3, zh = z & 7;
    const u16* Ab = awT + (long)z * 1048576;
    const u16* Bb = vT + (long)z * 65536;
    const int srow = tid >> 2, scol = (tid & 3) << 3;
    f32x4 acc[4] = {};
    for (int k0 = 0; k0 < 1024; k0 += 32) {
        load16(Ab + (long)(bm + srow) * 1024 + (k0 + scol), As + (w << 9));
        load16(Bb + (long)srow * 1024 + (k0 + scol),        Bs + (w << 9));
        __syncthreads();
        bf16x8 a = *(const bf16x8*)(As + ((w << 4) + l16) * 32 + (quad << 3));
#pragma unroll
        for (int c = 0; c < 4; ++c) {
            bf16x8 b = *(const bf16x8*)(Bs + ((c << 4) + l16) * 32 + (quad << 3));
            acc[c] = __builtin_amdgcn_mfma_f32_16x16x32_bf16(a, b, acc[c], 0, 0, 0);
        }
        __syncthreads();
    }
    float sc = stats[z];
    int rowb = bm + (w << 4) + (quad << 2);
    long base = (long)zb * 524288 + (long)zh * 64;
#pragma unroll
    for (int c = 0; c < 4; ++c) {
        int col = (c << 4) + l16;
#pragma unroll
        for (int r = 0; r < 4; ++r)
            attn[base + (long)(rowb + r) * 512 + col] = f2bf(acc[c][r] * sc);
    }
}

// final aw output: aw[z][i][j] = awT[z][j][i] * sc[z], 32x32 LDS tiles
__global__ __launch_bounds__(256) void aw_norm_k(const u16* __restrict__ awT,
                                                 const float* __restrict__ stats,
                                                 void* __restrict__ dout,
                                                 const int* __restrict__ dflag) {
    __shared__ u16 t[32][33];
    int z = blockIdx.z;
    float sc = stats[z];
    int i0 = blockIdx.x << 5, j0 = blockIdx.y << 5;
    int tx = threadIdx.x & 31, ty = threadIdx.x >> 5;   // ty 0..7
    const u16* src = awT + (long)z * 1048576;
#pragma unroll
    for (int r = 0; r < 4; ++r) {
        int j = j0 + ty + (r << 3);
        t[ty + (r << 3)][tx] = src[(long)j * 1024 + i0 + tx];
    }
    __syncthreads();
    long obase = 2097152 + (long)z * 1048576;
    int f32o = dflag[0];
#pragma unroll
    for (int r = 0; r < 4; ++r) {
        int i = i0 + ty + (r << 3);
        float v = bf2f(t[tx][ty + (r << 3)]) * sc;
        long oi = obase + (long)i * 1024 + j0 + tx;
        if (f32o) ((float*)dout)[oi] = v;
        else      ((u16*)dout)[oi] = f2bf(v);
    }
}

// 64x128 tile RES GEMM (C = A*Bt^T + bias + resid, fp32 out)
__global__ __launch_bounds__(256) void gemm_rw(
    const u16* __restrict__ A, int lda,
    const u16* __restrict__ Bt, int ldb,
    int K, const u16* __restrict__ bias,
    float* __restrict__ out0, int ldc,
    const float* __restrict__ resid)
{
    __shared__ __align__(16) u16 As[64 * 32];
    __shared__ __align__(16) u16 Bs[128 * 32];
    const int tid = threadIdx.x, w = tid >> 6, l = tid & 63;
    const int quad = l >> 4, l16 = l & 15;
    const int bm = blockIdx.x * 64, bn = blockIdx.y * 128;
    const int srow = tid >> 2, scol = (tid & 3) << 3;
    const int mwv = (w >> 1) << 5, nwv = (w & 1) << 6;
    f32x4 acc[2][4] = {};

    for (int k0 = 0; k0 < K; k0 += 32) {
        load16(A + (long)(bm + srow) * lda + (k0 + scol),       As + (w << 9));
        load16(Bt + (long)(bn + srow) * ldb + (k0 + scol),      Bs + (w << 9));
        load16(Bt + (long)(bn + 64 + srow) * ldb + (k0 + scol), Bs + 2048 + (w << 9));
        __syncthreads();
        bf16x8 a[2], b[4];
#pragma unroll
        for (int i = 0; i < 2; ++i)
            a[i] = *(const bf16x8*)(As + (mwv + (i << 4) + l16) * 32 + (quad << 3));
#pragma unroll
        for (int i = 0; i < 4; ++i)
            b[i] = *(const bf16x8*)(Bs + (nwv + (i << 4) + l16) * 32 + (quad << 3));
#pragma unroll
        for (int mi = 0; mi < 2; ++mi)
#pragma unroll
            for (int ni = 0; ni < 4; ++ni)
                acc[mi][ni] = __builtin_amdgcn_mfma_f32_16x16x32_bf16(a[mi], b[ni], acc[mi][ni], 0, 0, 0);
        __syncthreads();
    }
#pragma unroll
    for (int ni = 0; ni < 4; ++ni) {
        int col = bn + nwv + (ni << 4) + l16;
        float bv = bf2f(bias[col]);
#pragma unroll
        for (int mi = 0; mi < 2; ++mi) {
            int rowb = bm + mwv + (mi << 4) + (quad << 2);
#pragma unroll
            for (int r = 0; r < 4; ++r) {
                long row = rowb + r;
                out0[row * ldc + col] = acc[mi][ni][r] + bv + resid[row * DMODEL + col];
            }
        }
    }
}

__global__ __launch_bounds__(256) void layernorm_k(const float* __restrict__ in,
                                                   const u16* __restrict__ g,
                                                   const u16* __restrict__ bb,
                                                   float* __restrict__ outf,
                                                   void* __restrict__ outb,
                                                   const int* __restrict__ of) {
    __shared__ float red[8];
    int row = blockIdx.x, t = threadIdx.x, wave = t >> 6, lane = t & 63;
    const float* x = in + (long)row * DMODEL;
    float v0 = x[t], v1 = x[t + 256];
    float s = v0 + v1;
    for (int off = 32; off; off >>= 1) s += __shfl_xor(s, off);
    if (lane == 0) red[wave] = s;
    __syncthreads();
    float mean = (red[0] + red[1] + red[2] + red[3]) * (1.0f / 512.0f);
    float d0 = v0 - mean, d1 = v1 - mean;
    float q = d0 * d0 + d1 * d1;
    for (int off = 32; off; off >>= 1) q += __shfl_xor(q, off);
    if (lane == 0) red[4 + wave] = q;
    __syncthreads();
    float var = (red[4] + red[5] + red[6] + red[7]) * (1.0f / 512.0f);
    float inv = rsqrtf(var + 1e-9f);
    float o0 = bf2f(g[t]) * d0 * inv + bf2f(bb[t]);
    float o1 = bf2f(g[t + 256]) * d1 * inv + bf2f(bb[t + 256]);
    long base = (long)row * DMODEL;
    if (outf) { outf[base + t] = o0; outf[base + t + 256] = o1; }
    if (of && of[0]) {
        ((float*)outb)[base + t] = o0;
        ((float*)outb)[base + t + 256] = o1;
    } else {
        ((u16*)outb)[base + t] = f2bf(o0);
        ((u16*)outb)[base + t + 256] = f2bf(o1);
    }
}

extern "C" void kernel_launch(void* const* d_in, const int* in_sizes, int n_in,
                              void* d_out, int out_size, void* d_ws, size_t ws_size,
                              hipStream_t stream) {
    const void* x_in   = d_in[0];
    const void* maskr  = d_in[1];
    const int*  protok = (const int*)d_in[2];
    const void* wq_w = d_in[3];  const void* wq_b = d_in[4];
    const void* wk_w = d_in[5];  const void* wk_b = d_in[6];
    const void* wv_w = d_in[7];  const void* wv_b = d_in[8];
    const void* wo_w = d_in[9];  const void* wo_b = d_in[10];
    const void* w1   = d_in[11]; const void* b1   = d_in[12];
    const void* w2   = d_in[13]; const void* b2   = d_in[14];
    const void* ln1g = d_in[15]; const void* ln1b = d_in[16];
    const void* ln2g = d_in[17]; const void* ln2b = d_in[18];

    char* p = (char*)d_ws;
    auto alloc = [&](size_t bytes) { char* r = p; p += (bytes + 255) & ~(size_t)255; return (void*)r; };

    u16* wqkvT = (u16*)alloc((size_t)1536 * 512 * 2);
    u16* woT   = (u16*)alloc(512 * 512 * 2);
    u16* w1T   = (u16*)alloc((size_t)512 * 2048 * 2);
    u16* w2T   = (u16*)alloc((size_t)2048 * 512 * 2);
    u16* qb    = (u16*)alloc((size_t)4096 * 512 * 2);
    u16* kb    = (u16*)alloc((size_t)4096 * 512 * 2);
    u16* vT    = (u16*)alloc((size_t)32 * 64 * 1024 * 2);
    u16* attn  = (u16*)alloc((size_t)4096 * 512 * 2);
    u16* awT   = (u16*)alloc((size_t)32 * 1024 * 1024 * 2);   // 64 MB
    float* xcur  = (float*)alloc((size_t)4096 * 512 * 4);
    u16*   xbf   = (u16*)alloc((size_t)4096 * 512 * 2);
    float* resb  = (float*)alloc((size_t)4096 * 512 * 4);
    float* out1f = (float*)alloc((size_t)4096 * 512 * 4);
    u16*   out1b = (u16*)alloc((size_t)4096 * 512 * 2);
    u16*   ffnh  = (u16*)alloc((size_t)4096 * 2048 * 2);
    float* partials = (float*)alloc(32 * 64 * 4);
    float* stats    = (float*)alloc(32 * 4);
    float* rowc     = (float*)alloc(256);
    float* mzf      = (float*)alloc(4096 * 4);
    u16*   barena   = (u16*)alloc(8192 * 2);
    int*   dflag    = (int*)alloc(256);

    if ((size_t)(p - (char*)d_ws) > ws_size) return;

    detect_k<<<1, 256, 0, stream>>>((const unsigned int*)maskr, dflag);
    mega_setup<<<4111, 256, 0, stream>>>(
        wq_w, wk_w, wv_w, wo_w, w1, w2,
        wq_b, wk_b, wv_b, wo_b, b1, b2, ln1g, ln1b, ln2g, ln2b,
        protok, maskr, x_in, dflag,
        wqkvT, woT, w1T, w2T, barena, rowc, mzf, xbf, xcur);

    for (int layer = 0; layer < 4; ++layer) {
        gemm128<G_QKV><<<dim3(32, 12), 256, 0, stream>>>(
            xbf, 512, wqkvT, 512, 512, barena + 0, qb, 512, kb, vT);
        qk_exp<<<dim3(8, 8, 32), 256, 0, stream>>>(kb, qb, mzf, awT, partials);
        merge64<<<32, 64, 0, stream>>>(partials, stats, rowc);
        if (layer == 3)
            aw_norm_k<<<dim3(32, 32, 32), 256, 0, stream>>>(awT, stats, d_out, dflag);
        gemm_pv<<<dim3(16, 32), 256, 0, stream>>>(awT, vT, stats, attn);
        gemm_rw<<<dim3(64, 4), 256, 0, stream>>>(
            attn, 512, woT, 512, 512, barena + 1536, resb, 512, xcur);
        layernorm_k<<<4096, 256, 0, stream>>>(resb, barena + 4608, barena + 5120,
                                              out1f, out1b, nullptr);
        gemm128<G_RELU><<<dim3(32, 16), 256, 0, stream>>>(
            out1b, 512, w1T, 512, 512, barena + 2048, ffnh, 2048, nullptr, nullptr);
        gemm_rw<<<dim3(64, 4), 256, 0, stream>>>(
            ffnh, 2048, w2T, 2048, 2048, barena + 4096, resb, 512, out1f);
        layernorm_k<<<4096, 256, 0, stream>>>(resb, barena + 5632, barena + 6144,
                                              xcur, (layer == 3) ? d_out : (void*)xbf,
                                              (layer == 3) ? dflag : nullptr);
    }
}